// Round 3
// baseline (126.412 us; speedup 1.0000x reference)
//
#include <hip/hip_runtime.h>

// Sinkhorn fixed-point for fermionic canonical ensembles.
// B=2048 systems, P=64 orbitals, N_PART=32, n_iters from d_in[2].
//
// R15 = 2 systems per wave (R12's wave count: 1024 waves, 1/SIMD) but with
// the two systems SOFTWARE-PIPELINED half an iteration apart inside one
// instruction stream. R13/R14 post-mortem: giving each system its own wave
// raised per-SIMD issue 4230->5240 cyc/iter (duplicated shared work) and
// the SIMD wave-scheduler only partially decorrelated the pair (VALUBusy
// 58->64%, dur 74.9->68.3, still worse than R12's 60.9). R12's limit was
// the opposite: both systems in lockstep -> the 31-step sweep's ~1100-cyc
// carried chain had nothing to fill it (R11->R12 aux fusion was neutral =
// bubbles absorb free work but can't shrink). Here each system runs R13's
// exact full-wave code (F1 = stage+C_k+E+Er+x, F2 = fused sweep+aux, G =
// update+normalize), and the loop is rotated so system A's sweep is
// co-resident in the stream with system B's exp-dense F1 and vice versa:
//   A.F1; B.F1; A.F2;  { A.G; A.F1; B.F2 } x(n-1) interleaved both ways;
//   A.G; B.F2; B.G.
// Independent register chains -> the compiler's list scheduler interleaves
// them (ILP, not TLP). Per-system op sequence is exactly (F1 F2 G)^n ->
// bit-identical to R13/R12. 1024 blocks x 64 threads, waves_per_eu(1,1).
// Everything else identical to R13: per-system numpy op order,
// contract(off), Cody-Waite exp/log, ~1ulp rcp_nr, Er preload + volatile
// pins, barrier-bracketed LDS staging (single-wave block).
// CANARY: absmax must be exactly 0.015625.

#pragma clang fp contract(off)

#define NPART 32
#define PORB  64

#define L2E_HI 1.44269502162933349609375f
#define L2E_LO 1.9259629911266175e-08f
#define LN2_HI 0.69314718246459960938f
#define LN2_LO -1.9046542121259175e-09f
#define LN2F   0.6931471805599453f

__device__ __forceinline__ float readlane_f(float v, int srclane) {
    return __int_as_float(__builtin_amdgcn_readlane(__float_as_int(v), srclane));
}

// reciprocal: v_rcp_f32 + one Newton step => ~0.5-1 ulp
__device__ __forceinline__ float rcp_nr(float d) {
    float r = __builtin_amdgcn_rcpf(d);
    float e = fmaf(-d, r, 1.0f);
    return fmaf(r, e, r);
}

// e^arg with Cody-Waite correction (<=1.5 ulp), arg pre-rounded like numpy
__device__ __forceinline__ float exp_acc(float arg) {
    float p    = arg * L2E_HI;
    float perr = fmaf(arg, L2E_HI, -p);
    float c    = fmaf(arg, L2E_LO, perr);
    float e0   = __builtin_amdgcn_exp2f(p);
    return fmaf(e0, c * LN2F, e0);
}

// ln(x) = log2(x)*ln2 with split constant (~1.5 ulp)
__device__ __forceinline__ float ln_acc(float x) {
    float l2 = __log2f(x);
    float p  = l2 * LN2_HI;
    float e  = fmaf(l2, LN2_HI, -p);
    return p + fmaf(l2, LN2_LO, e);
}

// numpy pairwise_sum over one system's 64 orbitals, 1 orbital per lane.
// Identical values/order to R13's red64.
__device__ __forceinline__ float red64(float v, int lane) {
    float c = v;
    c = c + __shfl(v, (lane + 8)  & 63);
    c = c + __shfl(v, (lane + 16) & 63);
    c = c + __shfl(v, (lane + 24) & 63);
    c = c + __shfl(v, (lane + 32) & 63);
    c = c + __shfl(v, (lane + 40) & 63);
    c = c + __shfl(v, (lane + 48) & 63);
    c = c + __shfl(v, (lane + 56) & 63);
    return ((readlane_f(c, 0) + readlane_f(c, 1)) +
            (readlane_f(c, 2) + readlane_f(c, 3))) +
           ((readlane_f(c, 4) + readlane_f(c, 5)) +
            (readlane_f(c, 6) + readlane_f(c, 7)));
}

// Per-system iteration state. All member-array accesses use compile-time
// indices (unrolled) -> SROA keeps everything in VGPRs.
struct Sys {
    float eps, nn, ratio, inv_snn;   // persistent across iterations
    float x, c1v;                    // F1 -> F2
    float Er[NPART];                 // F1 -> F2 (E gathers, pinned)
    float Qp1, Qp0;                  // F2 -> G
};

// ---- setup: nn, snn, ratio, eps0 (per-orbital values == R13) ----
__device__ __forceinline__ void sys_setup(Sys& S, const float* __restrict__ nptr,
                                          int lane, float inv_beta) {
    const float n0   = nptr[lane];
    const float srt  = red64(n0, lane);
    const float isrt = rcp_nr(srt);
    S.nn      = (n0 * isrt) * (float)NPART;
    const float snn = red64(S.nn, lane);
    S.inv_snn = rcp_nr(snn);
    S.ratio   = S.nn * rcp_nr(1.0f - S.nn);
    S.eps     = (-ln_acc(S.ratio)) * inv_beta;
}

// ---- F1: stage eps, C_k, E, Er preload, x (identical ops to R13) ----
__device__ __forceinline__ void phase_F1(Sys& S, float* __restrict__ t_own,
                                         const float4* __restrict__ t4own,
                                         int lane, int l32, int h,
                                         float mk, float nb) {
    // stage eps (barrier-bracketed; single-wave block)
    __syncthreads();
    t_own[lane] = S.eps;
    __syncthreads();

    // C_k: lane (k-1, half h) builds numpy accumulators 4h..4h+3; uniform
    // address per half => broadcast, conflict-free. Same order as R13.
    float a0, a1, a2, a3;
    #pragma unroll
    for (int i = 0; i < 8; ++i) {
        const float4 va = t4own[2 * i + h];
        const float e0 = exp_acc(mk * va.x);
        const float e1 = exp_acc(mk * va.y);
        const float e2 = exp_acc(mk * va.z);
        const float e3 = exp_acc(mk * va.w);
        if (i == 0) { a0 = e0; a1 = e1; a2 = e2; a3 = e3; }
        else        { a0 += e0; a1 += e1; a2 += e2; a3 += e3; }
    }
    const float t = (a0 + a1) + (a2 + a3);   // tLo (h=0) / tHi (h=1)
    // C[k] = tLo + tHi == ((a0+a1)+(a2+a3)) + ((a4+a5)+(a6+a7))
    const float Cfull = __shfl(t, l32) + __shfl(t, l32 + 32);

    S.c1v = readlane_f(Cfull, 0);            // C[1]

    // E[i] = C[i+1]/C[i] (l32==0 junk, never consumed by live lanes)
    const float prevC = __shfl(Cfull, (l32 - 1) & 31);
    const float E     = Cfull * rcp_nr(prevC);

    // preload + pin the 31 E-gathers (R8 win)
    #pragma unroll
    for (int s = 1; s < NPART; ++s) {
        S.Er[s] = __shfl(E, (l32 + 1 - s) & 31);
        asm volatile("" : "+v"(S.Er[s]));    // schedule pin only
    }

    // aux input, hoisted (depends only on eps)
    S.x = exp_acc(nb * S.eps);
}

// ---- F2: fused sweep + aux (identical ops/order/rounding to R13) ----
__device__ __forceinline__ void phase_F2(Sys& S) {
    const float invQ0 = rcp_nr(S.c1v);
    float prev;
    {
        const float a = (S.x * invQ0) * 1.0f;   // prev = 1.0 initially
        prev = 1.0f - a;
    }
    float y30 = 0.0f;
    float invQprev = invQ0;                     // invQ[s-1] carry
    float p = 1.0f;
    #pragma unroll
    for (int s = 1; s < NPART; ++s) {
        const float d = S.Er[s] * invQprev;
        const float m = d * p;
        p = 1.0f - m;
        const float psv = readlane_f(p, s);
        const float invQs = (float)(s + 1) * rcp_nr(S.c1v * psv);
        // aux step s (inline g = x*invQ[s]; same rounding as R13)
        const float a = (S.x * invQs) * prev;
        prev = 1.0f - a;
        if (s == NPART - 2) y30 = prev;
        invQprev = invQs;
    }
    S.Qp1 = prev;
    S.Qp0 = y30 * invQprev;                     // invQ[NPART-1]
}

// ---- G: update + normalize (identical per-orbital ops to R13) ----
__device__ __forceinline__ void phase_G(Sys& S, int lane, float inv_beta) {
    const float q  = (S.ratio * S.Qp1) * rcp_nr(S.Qp0);
    const float en = (-ln_acc(q)) * inv_beta;
    const float W = red64(S.nn * en, lane);
    const float corr = W * S.inv_snn;
    S.eps = en - corr;
}

__global__ __launch_bounds__(PORB)
__attribute__((amdgpu_waves_per_eu(1, 1)))
void sinkhorn_kernel(
    const float* __restrict__ n_in,
    const float* __restrict__ beta_ptr,
    const int*   __restrict__ iters_ptr,
    float*       __restrict__ out)
{
    const int b    = blockIdx.x;                // pair index: A=2b, B=2b+1
    const int lane = threadIdx.x;               // orbital index
    const int l32  = lane & 31;
    const int h    = lane >> 5;                 // accumulator half for C_k

    const float beta    = beta_ptr[0];
    const int   n_iters = iters_ptr[0];
    const float nb      = -beta;
    const float inv_beta = rcp_nr(beta);

    __shared__ __align__(16) float t_sh[2 * PORB];  // eps staging, 2 systems
    float* tA = t_sh;
    float* tB = t_sh + PORB;
    const float4* t4A = reinterpret_cast<const float4*>(tA);
    const float4* t4B = reinterpret_cast<const float4*>(tB);

    const int baseA = (2 * b)     * PORB;
    const int baseB = (2 * b + 1) * PORB;

    Sys A, B;
    sys_setup(A, n_in + baseA, lane, inv_beta);
    sys_setup(B, n_in + baseB, lane, inv_beta);

    const float kf = (float)(l32 + 1);          // this lane's k (both halves)
    const float mk = nb * kf;

    if (n_iters > 0) {
        // ---- prologue: A a half-iteration ahead of B ----
        phase_F1(A, tA, t4A, lane, l32, h, mk, nb);
        phase_F1(B, tB, t4B, lane, l32, h, mk, nb);
        phase_F2(A);                             // mixes with B.F1's tail

        for (int it = 0; it < n_iters - 1; ++it) {
            // region 2: A finishes it & starts it+1; B's sweep chain (reg-
            // only, placed after A.F1's last barrier) fills A's issue gaps.
            phase_G(A, lane, inv_beta);
            phase_F1(A, tA, t4A, lane, l32, h, mk, nb);
            phase_F2(B);
            // region 1: B finishes it & starts it+1; A's sweep fills.
            phase_G(B, lane, inv_beta);
            phase_F1(B, tB, t4B, lane, l32, h, mk, nb);
            phase_F2(A);
        }

        // ---- epilogue ----
        phase_G(A, lane, inv_beta);
        phase_F2(B);
        phase_G(B, lane, inv_beta);
    }

    out[baseA + lane] = A.eps;
    out[baseB + lane] = B.eps;
}

extern "C" void kernel_launch(void* const* d_in, const int* in_sizes, int n_in,
                              void* d_out, int out_size, void* d_ws, size_t ws_size,
                              hipStream_t stream) {
    const float* n_ptr    = (const float*)d_in[0];
    const float* beta_ptr = (const float*)d_in[1];
    const int*   it_ptr   = (const int*)d_in[2];
    float*       out      = (float*)d_out;

    const int B = in_sizes[0] / PORB;   // 2048 systems, 2 per wave
    sinkhorn_kernel<<<B / 2, PORB, 0, stream>>>(n_ptr, beta_ptr, it_ptr, out);
}

// Round 4
// 115.804 us; speedup vs baseline: 1.0916x; 1.0916x over previous
//
#include <hip/hip_runtime.h>

// Sinkhorn fixed-point for fermionic canonical ensembles.
// B=2048 systems, P=64 orbitals, N_PART=32, n_iters from d_in[2].
//
// R16 = R12 (best verified: 60.9us kernel, 2 systems/wave SIMD-packed,
// 1024 waves = 1/SIMD) + SCALAR-PIPELINED SWEEP BROADCAST.
// R13/R14/R15 post-mortem: combined VALUBusy across all occupancy/pipeline
// variants follows 1-(1-d)^2 of the single-stream duty -> the wave
// scheduler was never the problem; every de-sharing of R12's SIMD-packed
// stream raised issue ~25% and lost. Remaining lever: R12's sweep carried
// chain (31 steps x ~48cy = readlane(+SGPR-hazard nops) -> mul -> rcp_nr
// -> mul). Fix: Er[s]@lane s == E[1|hbit] for all s, so the broadcast
// value psv_s = p_s@lane s obeys a uniform-per-half shadow recursion
//   psv_s = 1 - (E1v*invQ[s-1])*u_s,   u_s = p_{s-1}@lane s,
// where u_s is readlane'd one step EARLY (right after step s-1's p
// update), overlapping the previous step's rcp. The shadow ops multiply
// the same operand values in the same order as the lane-s slice of the
// vector recursion -> psv, invQs and everything downstream bit-identical.
// Chain/step 48 -> ~36 cy, readlane+hazards off the carried chain.
// Everything else VERBATIM R12: pack-2 systems/wave, per-system numpy op
// order, contract(off), Cody-Waite exp/log, ~1ulp rcp_nr, Er preload +
// volatile pins, waves_per_eu(1,1), barrier-bracketed LDS staging.
// CANARY: absmax must be exactly 0.015625.

#pragma clang fp contract(off)

#define NPART 32
#define PORB  64

#define L2E_HI 1.44269502162933349609375f
#define L2E_LO 1.9259629911266175e-08f
#define LN2_HI 0.69314718246459960938f
#define LN2_LO -1.9046542121259175e-09f
#define LN2F   0.6931471805599453f

__device__ __forceinline__ float readlane_f(float v, int srclane) {
    return __int_as_float(__builtin_amdgcn_readlane(__float_as_int(v), srclane));
}

// reciprocal: v_rcp_f32 + one Newton step => ~0.5-1 ulp
__device__ __forceinline__ float rcp_nr(float d) {
    float r = __builtin_amdgcn_rcpf(d);
    float e = fmaf(-d, r, 1.0f);
    return fmaf(r, e, r);
}

// e^arg with Cody-Waite correction (<=1.5 ulp), arg pre-rounded like numpy
__device__ __forceinline__ float exp_acc(float arg) {
    float p    = arg * L2E_HI;
    float perr = fmaf(arg, L2E_HI, -p);
    float c    = fmaf(arg, L2E_LO, perr);
    float e0   = __builtin_amdgcn_exp2f(p);
    return fmaf(e0, c * LN2F, e0);
}

// ln(x) = log2(x)*ln2 with split constant (~1.5 ulp)
__device__ __forceinline__ float ln_acc(float x) {
    float l2 = __log2f(x);
    float p  = l2 * LN2_HI;
    float e  = fmaf(l2, LN2_HI, -p);
    return p + fmaf(l2, LN2_LO, e);
}

// shuffle within the lane's own 32-lane half
__device__ __forceinline__ float shfl32(float v, int idx, int hbit) {
    return __shfl(v, (idx & 31) | hbit);
}

// numpy pairwise_sum over one system's 64 orbitals (identical to R12)
__device__ __forceinline__ float red_np(float v0, float v1, int l32, int hbit) {
    float c = v0;
    c = c + shfl32(v0, l32 + 8,  hbit);
    c = c + shfl32(v0, l32 + 16, hbit);
    c = c + shfl32(v0, l32 + 24, hbit);
    c = c + v1;
    c = c + shfl32(v1, l32 + 8,  hbit);
    c = c + shfl32(v1, l32 + 16, hbit);
    c = c + shfl32(v1, l32 + 24, hbit);
    const float ta = ((readlane_f(c, 0) + readlane_f(c, 1)) +
                      (readlane_f(c, 2) + readlane_f(c, 3))) +
                     ((readlane_f(c, 4) + readlane_f(c, 5)) +
                      (readlane_f(c, 6) + readlane_f(c, 7)));
    const float tb = ((readlane_f(c, 32) + readlane_f(c, 33)) +
                      (readlane_f(c, 34) + readlane_f(c, 35))) +
                     ((readlane_f(c, 36) + readlane_f(c, 37)) +
                      (readlane_f(c, 38) + readlane_f(c, 39)));
    return hbit ? tb : ta;
}

__global__ __launch_bounds__(PORB)
__attribute__((amdgpu_waves_per_eu(1, 1)))
void sinkhorn_kernel(
    const float* __restrict__ n_in,
    const float* __restrict__ beta_ptr,
    const int*   __restrict__ iters_ptr,
    float*       __restrict__ out)
{
    const int b    = blockIdx.x;                // pair index
    const int lane = threadIdx.x;
    const int l32  = lane & 31;
    const int hbit = lane & 32;                 // 0 (system A) / 32 (system B)
    const int h    = hbit >> 5;

    const float beta    = beta_ptr[0];
    const int   n_iters = iters_ptr[0];
    const float nb      = -beta;
    const float inv_beta = rcp_nr(beta);

    __shared__ __align__(16) float t_sh[2 * PORB];  // eps staging, 2 systems

    const int sysbase = (2 * b + h) * PORB;
    const float n0 = n_in[sysbase + l32];           // orbital l32
    const float n1 = n_in[sysbase + 32 + l32];      // orbital l32+32

    // ---- setup: nn, snn, ratio, eps0 (per-system values == R12) ----
    const float srt  = red_np(n0, n1, l32, hbit);
    const float isrt = rcp_nr(srt);
    const float nn0  = (n0 * isrt) * (float)NPART;
    const float nn1  = (n1 * isrt) * (float)NPART;
    const float snn  = red_np(nn0, nn1, l32, hbit);
    const float inv_snn = rcp_nr(snn);
    const float ratio0  = nn0 * rcp_nr(1.0f - nn0);
    const float ratio1  = nn1 * rcp_nr(1.0f - nn1);
    float eps0 = (-ln_acc(ratio0)) * inv_beta;
    float eps1 = (-ln_acc(ratio1)) * inv_beta;

    const float kf = (float)(l32 + 1);              // this lane's k
    const float mk = nb * kf;

    for (int it = 0; it < n_iters; ++it) {
        // ---- stage both systems' eps (barrier-bracketed fences) ----
        __syncthreads();
        t_sh[2 * hbit + l32]      = eps0;           // 2*hbit == h*64
        t_sh[2 * hbit + 32 + l32] = eps1;
        __syncthreads();

        // ---- C_k: lane k-1 of each half builds all 8 numpy accumulators
        // (identical values/order to R12); 2x ds_read_b128 per i, uniform
        // address per half => broadcast, conflict-free.
        const float4* t4 = reinterpret_cast<const float4*>(t_sh);
        float acc[8];
        #pragma unroll
        for (int i = 0; i < 8; ++i) {
            const float4 va = t4[(h << 4) + 2 * i];      // eps[8i .. 8i+3]
            const float4 vb = t4[(h << 4) + 2 * i + 1];  // eps[8i+4 .. 8i+7]
            const float e0 = exp_acc(mk * va.x);
            const float e1 = exp_acc(mk * va.y);
            const float e2 = exp_acc(mk * va.z);
            const float e3 = exp_acc(mk * va.w);
            const float e4 = exp_acc(mk * vb.x);
            const float e5 = exp_acc(mk * vb.y);
            const float e6 = exp_acc(mk * vb.z);
            const float e7 = exp_acc(mk * vb.w);
            if (i == 0) {
                acc[0] = e0; acc[1] = e1; acc[2] = e2; acc[3] = e3;
                acc[4] = e4; acc[5] = e5; acc[6] = e6; acc[7] = e7;
            } else {
                acc[0] += e0; acc[1] += e1; acc[2] += e2; acc[3] += e3;
                acc[4] += e4; acc[5] += e5; acc[6] += e6; acc[7] += e7;
            }
        }
        const float Cfull = ((acc[0] + acc[1]) + (acc[2] + acc[3])) +
                            ((acc[4] + acc[5]) + (acc[6] + acc[7]));
        // lane hbit + (k-1) holds C[k] of its system

        const float c1A = readlane_f(Cfull, 0);
        const float c1B = readlane_f(Cfull, 32);
        const float c1v = hbit ? c1B : c1A;          // per-half C[1]

        // E[i] = C[i+1]/C[i] (l32==0 junk, never consumed by live lanes)
        const float prevC = __shfl(Cfull, ((l32 - 1) & 31) | hbit);
        const float E     = Cfull * rcp_nr(prevC);

        // E[1] per half (uniform): Er[s]@lane s == E[1|hbit] for every s
        const float E1v = shfl32(E, 1, hbit);

        // ---- preload + pin the 31 E-gathers (R8 win) ----
        float Er[NPART];
        #pragma unroll
        for (int s = 1; s < NPART; ++s) {
            Er[s] = __shfl(E, ((l32 + 1 - s) & 31) | hbit);
            asm volatile("" : "+v"(Er[s]));          // schedule pin only
        }

        // ---- aux inputs, hoisted (depend only on eps) ----
        const float x0 = exp_acc(nb * eps0);
        const float x1 = exp_acc(nb * eps1);

        // ---- fused sweep + aux with scalar-pipelined broadcast:
        // psv_s computed by the uniform shadow recursion (bit-identical to
        // readlane(p_s, s|hbit)); the readlane that feeds u_{s+1} is issued
        // right after the p update, OFF the invQ carried chain.
        const float invQ0 = rcp_nr(c1v);
        // aux step 0 (prev = 1.0 initially; g*1.0 is exact)
        float prev0, prev1;
        {
            const float a0 = (x0 * invQ0) * 1.0f;
            prev0 = 1.0f - a0;
            const float a1 = (x1 * invQ0) * 1.0f;
            prev1 = 1.0f - a1;
        }
        float y30_0 = 0.0f, y30_1 = 0.0f;
        float invQprev = invQ0;                      // invQ[s-1] carry
        float p = 1.0f;
        float u = 1.0f;                              // p_{s-1}@lane s (uniform/half)
        #pragma unroll
        for (int s = 1; s < NPART; ++s) {
            // uniform shadow recursion: same operand values, same op order
            // as the lane-s slice of the vector recursion -> bit-identical.
            const float dS  = E1v * invQprev;        // == d @ lane s
            const float mS  = dS * u;                // == m @ lane s
            const float psv = 1.0f - mS;             // == p_s @ lane s
            // vector recursion (unchanged ops -> p trajectory identical)
            const float d = Er[s] * invQprev;
            const float m = d * p;
            p = 1.0f - m;
            // prefetch u_{s+1} = p_s @ lane s+1 (off the carried chain)
            if (s < NPART - 1) {
                const float uA = readlane_f(p, s + 1);
                const float uB = readlane_f(p, 32 + s + 1);
                u = hbit ? uB : uA;
            }
            const float invQs = (float)(s + 1) * rcp_nr(c1v * psv);
            // aux step s (inline g = x*invQ[s]; same rounding as R12)
            const float a0 = (x0 * invQs) * prev0;
            prev0 = 1.0f - a0;
            const float a1 = (x1 * invQs) * prev1;
            prev1 = 1.0f - a1;
            if (s == NPART - 2) { y30_0 = prev0; y30_1 = prev1; }
            invQprev = invQs;
        }
        const float invQ31 = invQprev;               // invQ[NPART-1]
        const float Qp1_0 = prev0,          Qp1_1 = prev1;
        const float Qp0_0 = y30_0 * invQ31;
        const float Qp0_1 = y30_1 * invQ31;

        // ---- update + normalize (identical to R12) ----
        const float q0 = (ratio0 * Qp1_0) * rcp_nr(Qp0_0);
        const float q1 = (ratio1 * Qp1_1) * rcp_nr(Qp0_1);
        const float en0 = (-ln_acc(q0)) * inv_beta;
        const float en1 = (-ln_acc(q1)) * inv_beta;

        const float W = red_np(nn0 * en0, nn1 * en1, l32, hbit);
        const float corr = W * inv_snn;
        eps0 = en0 - corr;
        eps1 = en1 - corr;
    }

    out[sysbase + l32]      = eps0;
    out[sysbase + 32 + l32] = eps1;
}

extern "C" void kernel_launch(void* const* d_in, const int* in_sizes, int n_in,
                              void* d_out, int out_size, void* d_ws, size_t ws_size,
                              hipStream_t stream) {
    const float* n_ptr    = (const float*)d_in[0];
    const float* beta_ptr = (const float*)d_in[1];
    const int*   it_ptr   = (const int*)d_in[2];
    float*       out      = (float*)d_out;

    const int B = in_sizes[0] / PORB;   // 2048 systems
    sinkhorn_kernel<<<B / 2, PORB, 0, stream>>>(n_ptr, beta_ptr, it_ptr, out);
}

// Round 5
// 109.026 us; speedup vs baseline: 1.1595x; 1.0622x over previous
//
#include <hip/hip_runtime.h>

// Sinkhorn fixed-point for fermionic canonical ensembles.
// B=2048 systems, P=64 orbitals, N_PART=32, n_iters from d_in[2].
//
// R17 = R12 (best verified: 60.9us kernel, 2 systems/wave SIMD-packed,
// 1024 waves = 1/SIMD, waves_per_eu(1,1)) + PACKED DUAL-FP32 (VOP3P).
// R13-R16 post-mortem: every structural rewrite (TLP, phase rotation,
// 2-stream SWP, shadow-scalar sweep) raised issue or disturbed the
// schedule and lost 6-17us; R12's single SIMD-packed stream is
// issue-minimal at ~4230 issue cyc/iter + ~3070 stall. R17 keeps R12's
// structure VERBATIM and attacks the issue count itself: gfx950's
// v_pk_{mul,add,fma}_f32 performs two independent IEEE-exact f32 ops per
// instruction. R12's hot code is naturally paired: C_k processes exps in
// pairs (14 scalar instr/pair -> 8 packed), the aux recursion carries
// (sys0,sys1) in lockstep (6 -> 3 per step), and q/en/W muls pair across
// systems. Expressed as ext_vector_type(2) arithmetic; per-element values
// are BIT-IDENTICAL (v_pk = same IEEE op per half), so absmax is
// unchanged by construction. Est. issue saving ~650 cyc/iter of 4230.
// Everything else VERBATIM R12: pack-2 systems/wave, per-system numpy op
// order, contract(off), Cody-Waite exp/log, ~1ulp rcp_nr, Er preload +
// volatile pins, barrier-bracketed LDS staging, readlane+cndmask sweep
// broadcast (R16's shadow recursion reverted: -6us).
// CANARY: absmax must be exactly 0.015625.

#pragma clang fp contract(off)

#define NPART 32
#define PORB  64

#define L2E_HI 1.44269502162933349609375f
#define L2E_LO 1.9259629911266175e-08f
#define LN2_HI 0.69314718246459960938f
#define LN2_LO -1.9046542121259175e-09f
#define LN2F   0.6931471805599453f

typedef float f32x2 __attribute__((ext_vector_type(2)));

__device__ __forceinline__ f32x2 pk(float a, float b) {
    f32x2 r; r.x = a; r.y = b; return r;
}

__device__ __forceinline__ float readlane_f(float v, int srclane) {
    return __int_as_float(__builtin_amdgcn_readlane(__float_as_int(v), srclane));
}

// reciprocal: v_rcp_f32 + one Newton step => ~0.5-1 ulp
__device__ __forceinline__ float rcp_nr(float d) {
    float r = __builtin_amdgcn_rcpf(d);
    float e = fmaf(-d, r, 1.0f);
    return fmaf(r, e, r);
}

// Packed e^arg pair with Cody-Waite correction. Per-element ops/order are
// IDENTICAL to R12's scalar exp_acc (v_pk_* = same IEEE op per half):
//   p=arg*L2E_HI; perr=fma(arg,L2E_HI,-p); c=fma(arg,L2E_LO,perr);
//   e0=exp2(p); r=fma(e0, c*LN2F, e0)
__device__ __forceinline__ f32x2 exp_pair(f32x2 arg) {
    const f32x2 HI = pk(L2E_HI, L2E_HI);
    const f32x2 LO = pk(L2E_LO, L2E_LO);
    const f32x2 LN = pk(LN2F,   LN2F);
    const f32x2 p    = arg * HI;                              // v_pk_mul
    const f32x2 perr = __builtin_elementwise_fma(arg, HI, -p); // v_pk_fma
    const f32x2 c    = __builtin_elementwise_fma(arg, LO, perr);
    const f32x2 cl   = c * LN;
    f32x2 e;
    e.x = __builtin_amdgcn_exp2f(p.x);
    e.y = __builtin_amdgcn_exp2f(p.y);
    return __builtin_elementwise_fma(e, cl, e);               // v_pk_fma
}

// ln(x) = log2(x)*ln2 with split constant (~1.5 ulp)
__device__ __forceinline__ float ln_acc(float x) {
    float l2 = __log2f(x);
    float p  = l2 * LN2_HI;
    float e  = fmaf(l2, LN2_HI, -p);
    return p + fmaf(l2, LN2_LO, e);
}

// shuffle within the lane's own 32-lane half
__device__ __forceinline__ float shfl32(float v, int idx, int hbit) {
    return __shfl(v, (idx & 31) | hbit);
}

// numpy pairwise_sum over one system's 64 orbitals (identical to R12)
__device__ __forceinline__ float red_np(float v0, float v1, int l32, int hbit) {
    float c = v0;
    c = c + shfl32(v0, l32 + 8,  hbit);
    c = c + shfl32(v0, l32 + 16, hbit);
    c = c + shfl32(v0, l32 + 24, hbit);
    c = c + v1;
    c = c + shfl32(v1, l32 + 8,  hbit);
    c = c + shfl32(v1, l32 + 16, hbit);
    c = c + shfl32(v1, l32 + 24, hbit);
    const float ta = ((readlane_f(c, 0) + readlane_f(c, 1)) +
                      (readlane_f(c, 2) + readlane_f(c, 3))) +
                     ((readlane_f(c, 4) + readlane_f(c, 5)) +
                      (readlane_f(c, 6) + readlane_f(c, 7)));
    const float tb = ((readlane_f(c, 32) + readlane_f(c, 33)) +
                      (readlane_f(c, 34) + readlane_f(c, 35))) +
                     ((readlane_f(c, 36) + readlane_f(c, 37)) +
                      (readlane_f(c, 38) + readlane_f(c, 39)));
    return hbit ? tb : ta;
}

__global__ __launch_bounds__(PORB)
__attribute__((amdgpu_waves_per_eu(1, 1)))
void sinkhorn_kernel(
    const float* __restrict__ n_in,
    const float* __restrict__ beta_ptr,
    const int*   __restrict__ iters_ptr,
    float*       __restrict__ out)
{
    const int b    = blockIdx.x;                // pair index
    const int lane = threadIdx.x;
    const int l32  = lane & 31;
    const int hbit = lane & 32;                 // 0 (system A) / 32 (system B)
    const int h    = hbit >> 5;

    const float beta    = beta_ptr[0];
    const int   n_iters = iters_ptr[0];
    const float nb      = -beta;
    const float inv_beta = rcp_nr(beta);

    __shared__ __align__(16) float t_sh[2 * PORB];  // eps staging, 2 systems

    const int sysbase = (2 * b + h) * PORB;
    const float n0 = n_in[sysbase + l32];           // orbital l32
    const float n1 = n_in[sysbase + 32 + l32];      // orbital l32+32

    // ---- setup: nn, snn, ratio, eps0 (per-system values == R12) ----
    const float srt  = red_np(n0, n1, l32, hbit);
    const float isrt = rcp_nr(srt);
    const float nn0  = (n0 * isrt) * (float)NPART;
    const float nn1  = (n1 * isrt) * (float)NPART;
    const float snn  = red_np(nn0, nn1, l32, hbit);
    const float inv_snn = rcp_nr(snn);
    const float ratio0  = nn0 * rcp_nr(1.0f - nn0);
    const float ratio1  = nn1 * rcp_nr(1.0f - nn1);
    float eps0 = (-ln_acc(ratio0)) * inv_beta;
    float eps1 = (-ln_acc(ratio1)) * inv_beta;

    const f32x2 nn2    = pk(nn0, nn1);
    const f32x2 ratio2 = pk(ratio0, ratio1);
    const f32x2 one2   = pk(1.0f, 1.0f);

    const float kf  = (float)(l32 + 1);             // this lane's k
    const float mk  = nb * kf;
    const f32x2 mk2 = pk(mk, mk);
    const f32x2 nb2 = pk(nb, nb);

    for (int it = 0; it < n_iters; ++it) {
        // ---- stage both systems' eps (barrier-bracketed fences) ----
        __syncthreads();
        t_sh[2 * hbit + l32]      = eps0;           // 2*hbit == h*64
        t_sh[2 * hbit + 32 + l32] = eps1;
        __syncthreads();

        // ---- C_k: lane k-1 of each half builds all 8 numpy accumulators
        // (identical values/order to R12, pairwise-packed); 2x ds_read_b128
        // per i, uniform address per half => broadcast, conflict-free.
        // acc2[j] = {acc[2j], acc[2j+1]} of R12.
        const float4* t4 = reinterpret_cast<const float4*>(t_sh);
        f32x2 acc2[4];
        #pragma unroll
        for (int i = 0; i < 8; ++i) {
            const float4 va = t4[(h << 4) + 2 * i];      // eps[8i .. 8i+3]
            const float4 vb = t4[(h << 4) + 2 * i + 1];  // eps[8i+4 .. 8i+7]
            const f32x2 r01 = exp_pair(mk2 * pk(va.x, va.y));
            const f32x2 r23 = exp_pair(mk2 * pk(va.z, va.w));
            const f32x2 r45 = exp_pair(mk2 * pk(vb.x, vb.y));
            const f32x2 r67 = exp_pair(mk2 * pk(vb.z, vb.w));
            if (i == 0) {
                acc2[0] = r01; acc2[1] = r23; acc2[2] = r45; acc2[3] = r67;
            } else {
                acc2[0] += r01; acc2[1] += r23; acc2[2] += r45; acc2[3] += r67;
            }
        }
        // ((a0+a1)+(a2+a3)) + ((a4+a5)+(a6+a7)) -- same tree as R12
        const float Cfull = ((acc2[0].x + acc2[0].y) + (acc2[1].x + acc2[1].y)) +
                            ((acc2[2].x + acc2[2].y) + (acc2[3].x + acc2[3].y));
        // lane hbit + (k-1) holds C[k] of its system

        const float c1A = readlane_f(Cfull, 0);
        const float c1B = readlane_f(Cfull, 32);
        const float c1v = hbit ? c1B : c1A;          // per-half C[1]

        // E[i] = C[i+1]/C[i] (l32==0 junk, never consumed by live lanes)
        const float prevC = __shfl(Cfull, ((l32 - 1) & 31) | hbit);
        const float E     = Cfull * rcp_nr(prevC);

        // ---- preload + pin the 31 E-gathers (R8 win) ----
        float Er[NPART];
        #pragma unroll
        for (int s = 1; s < NPART; ++s) {
            Er[s] = __shfl(E, ((l32 + 1 - s) & 31) | hbit);
            asm volatile("" : "+v"(Er[s]));          // schedule pin only
        }

        // ---- aux inputs, hoisted (depend only on eps); packed pair ----
        const f32x2 x2 = exp_pair(nb2 * pk(eps0, eps1));

        // ---- fused sweep + aux (R12 structure; aux pair packed):
        // per-element aux ops/order identical to R12.
        const float invQ0 = rcp_nr(c1v);
        // aux step 0 (prev = 1.0 initially; g*1.0 is exact)
        f32x2 prev2;
        {
            const f32x2 a2 = (x2 * pk(invQ0, invQ0)) * one2;
            prev2 = one2 - a2;
        }
        f32x2 y30_2 = pk(0.0f, 0.0f);
        float invQprev = invQ0;                      // invQ[s-1] carry
        float p = 1.0f;
        #pragma unroll
        for (int s = 1; s < NPART; ++s) {
            const float d = Er[s] * invQprev;
            const float m = d * p;
            p = 1.0f - m;
            const float psA = readlane_f(p, s);
            const float psB = readlane_f(p, 32 + s);
            const float psv = hbit ? psB : psA;
            const float invQs = (float)(s + 1) * rcp_nr(c1v * psv);
            // aux step s (packed; per-half == R12's (x*invQs)*prev; 1-a)
            const f32x2 a2 = (x2 * pk(invQs, invQs)) * prev2;
            prev2 = one2 - a2;
            if (s == NPART - 2) y30_2 = prev2;
            invQprev = invQs;
        }
        const float invQ31 = invQprev;               // invQ[NPART-1]
        const f32x2 Qp1_2  = prev2;
        const f32x2 Qp0_2  = y30_2 * pk(invQ31, invQ31);

        // ---- update + normalize (per-element ops identical to R12) ----
        const f32x2 q2 = (ratio2 * Qp1_2) * pk(rcp_nr(Qp0_2.x), rcp_nr(Qp0_2.y));
        const float en0 = (-ln_acc(q2.x)) * inv_beta;
        const float en1 = (-ln_acc(q2.y)) * inv_beta;

        const f32x2 w2 = nn2 * pk(en0, en1);         // {nn0*en0, nn1*en1}
        const float W = red_np(w2.x, w2.y, l32, hbit);
        const float corr = W * inv_snn;
        eps0 = en0 - corr;
        eps1 = en1 - corr;
    }

    out[sysbase + l32]      = eps0;
    out[sysbase + 32 + l32] = eps1;
}

extern "C" void kernel_launch(void* const* d_in, const int* in_sizes, int n_in,
                              void* d_out, int out_size, void* d_ws, size_t ws_size,
                              hipStream_t stream) {
    const float* n_ptr    = (const float*)d_in[0];
    const float* beta_ptr = (const float*)d_in[1];
    const int*   it_ptr   = (const int*)d_in[2];
    float*       out      = (float*)d_out;

    const int B = in_sizes[0] / PORB;   // 2048 systems
    sinkhorn_kernel<<<B / 2, PORB, 0, stream>>>(n_ptr, beta_ptr, it_ptr, out);
}

// Round 6
// 104.725 us; speedup vs baseline: 1.2071x; 1.0411x over previous
//
#include <hip/hip_runtime.h>

// Sinkhorn fixed-point for fermionic canonical ensembles.
// B=2048 systems, P=64 orbitals, N_PART=32, n_iters from d_in[2].
//
// R18 = R17 (best: 60.0us kernel, 2 systems/wave SIMD-packed + VOP3P
// packed dual-f32) + BATCHED LDS LOADS in C_k.
// R17 post-mortem: issue cut (~550cy/iter, VALUBusy 58->50.4%) converted
// to only ~110cy/iter of wall -> kernel is stall-bound at the program
// counter, ~3600 stall cyc/iter. ~2000 of those are unattributed by chain
// arithmetic; prime suspect is ds_read latency in C_k: at 1 wave/SIMD a
// single-outstanding ds_read is ~120cy, and the loop interleaves 16
// ds_read_b128 with consumers -> potential serial 120cy lgkm stalls with
// no partner wave to cover. Fix (zero arithmetic change): issue all 16
// float4 loads back-to-back (pipelined ~180cy total), compute x2 =
// exp_pair(nb*eps) (register-only) inside the load shadow, pin loaded
// values with empty asm (prevents the scheduler sinking loads back into
// compute), then run the IDENTICAL C_k arithmetic from registers.
// VGPR ~132->~196 (+64 payload), harmless at waves_per_eu(1,1).
// Everything else VERBATIM R17: pack-2 systems/wave, per-system numpy op
// order, contract(off), Cody-Waite exp/log (packed v_pk_* = same IEEE op
// per half), ~1ulp rcp_nr, Er preload + volatile pins, barrier-bracketed
// LDS staging, readlane+cndmask sweep broadcast, packed aux-in-sweep.
// CANARY: absmax must be exactly 0.015625.

#pragma clang fp contract(off)

#define NPART 32
#define PORB  64

#define L2E_HI 1.44269502162933349609375f
#define L2E_LO 1.9259629911266175e-08f
#define LN2_HI 0.69314718246459960938f
#define LN2_LO -1.9046542121259175e-09f
#define LN2F   0.6931471805599453f

typedef float f32x2 __attribute__((ext_vector_type(2)));

__device__ __forceinline__ f32x2 pk(float a, float b) {
    f32x2 r; r.x = a; r.y = b; return r;
}

__device__ __forceinline__ float readlane_f(float v, int srclane) {
    return __int_as_float(__builtin_amdgcn_readlane(__float_as_int(v), srclane));
}

// reciprocal: v_rcp_f32 + one Newton step => ~0.5-1 ulp
__device__ __forceinline__ float rcp_nr(float d) {
    float r = __builtin_amdgcn_rcpf(d);
    float e = fmaf(-d, r, 1.0f);
    return fmaf(r, e, r);
}

// Packed e^arg pair with Cody-Waite correction. Per-element ops/order are
// IDENTICAL to R12's scalar exp_acc (v_pk_* = same IEEE op per half):
//   p=arg*L2E_HI; perr=fma(arg,L2E_HI,-p); c=fma(arg,L2E_LO,perr);
//   e0=exp2(p); r=fma(e0, c*LN2F, e0)
__device__ __forceinline__ f32x2 exp_pair(f32x2 arg) {
    const f32x2 HI = pk(L2E_HI, L2E_HI);
    const f32x2 LO = pk(L2E_LO, L2E_LO);
    const f32x2 LN = pk(LN2F,   LN2F);
    const f32x2 p    = arg * HI;                              // v_pk_mul
    const f32x2 perr = __builtin_elementwise_fma(arg, HI, -p); // v_pk_fma
    const f32x2 c    = __builtin_elementwise_fma(arg, LO, perr);
    const f32x2 cl   = c * LN;
    f32x2 e;
    e.x = __builtin_amdgcn_exp2f(p.x);
    e.y = __builtin_amdgcn_exp2f(p.y);
    return __builtin_elementwise_fma(e, cl, e);               // v_pk_fma
}

// ln(x) = log2(x)*ln2 with split constant (~1.5 ulp)
__device__ __forceinline__ float ln_acc(float x) {
    float l2 = __log2f(x);
    float p  = l2 * LN2_HI;
    float e  = fmaf(l2, LN2_HI, -p);
    return p + fmaf(l2, LN2_LO, e);
}

// shuffle within the lane's own 32-lane half
__device__ __forceinline__ float shfl32(float v, int idx, int hbit) {
    return __shfl(v, (idx & 31) | hbit);
}

// numpy pairwise_sum over one system's 64 orbitals (identical to R12)
__device__ __forceinline__ float red_np(float v0, float v1, int l32, int hbit) {
    float c = v0;
    c = c + shfl32(v0, l32 + 8,  hbit);
    c = c + shfl32(v0, l32 + 16, hbit);
    c = c + shfl32(v0, l32 + 24, hbit);
    c = c + v1;
    c = c + shfl32(v1, l32 + 8,  hbit);
    c = c + shfl32(v1, l32 + 16, hbit);
    c = c + shfl32(v1, l32 + 24, hbit);
    const float ta = ((readlane_f(c, 0) + readlane_f(c, 1)) +
                      (readlane_f(c, 2) + readlane_f(c, 3))) +
                     ((readlane_f(c, 4) + readlane_f(c, 5)) +
                      (readlane_f(c, 6) + readlane_f(c, 7)));
    const float tb = ((readlane_f(c, 32) + readlane_f(c, 33)) +
                      (readlane_f(c, 34) + readlane_f(c, 35))) +
                     ((readlane_f(c, 36) + readlane_f(c, 37)) +
                      (readlane_f(c, 38) + readlane_f(c, 39)));
    return hbit ? tb : ta;
}

__global__ __launch_bounds__(PORB)
__attribute__((amdgpu_waves_per_eu(1, 1)))
void sinkhorn_kernel(
    const float* __restrict__ n_in,
    const float* __restrict__ beta_ptr,
    const int*   __restrict__ iters_ptr,
    float*       __restrict__ out)
{
    const int b    = blockIdx.x;                // pair index
    const int lane = threadIdx.x;
    const int l32  = lane & 31;
    const int hbit = lane & 32;                 // 0 (system A) / 32 (system B)
    const int h    = hbit >> 5;

    const float beta    = beta_ptr[0];
    const int   n_iters = iters_ptr[0];
    const float nb      = -beta;
    const float inv_beta = rcp_nr(beta);

    __shared__ __align__(16) float t_sh[2 * PORB];  // eps staging, 2 systems

    const int sysbase = (2 * b + h) * PORB;
    const float n0 = n_in[sysbase + l32];           // orbital l32
    const float n1 = n_in[sysbase + 32 + l32];      // orbital l32+32

    // ---- setup: nn, snn, ratio, eps0 (per-system values == R12) ----
    const float srt  = red_np(n0, n1, l32, hbit);
    const float isrt = rcp_nr(srt);
    const float nn0  = (n0 * isrt) * (float)NPART;
    const float nn1  = (n1 * isrt) * (float)NPART;
    const float snn  = red_np(nn0, nn1, l32, hbit);
    const float inv_snn = rcp_nr(snn);
    const float ratio0  = nn0 * rcp_nr(1.0f - nn0);
    const float ratio1  = nn1 * rcp_nr(1.0f - nn1);
    float eps0 = (-ln_acc(ratio0)) * inv_beta;
    float eps1 = (-ln_acc(ratio1)) * inv_beta;

    const f32x2 nn2    = pk(nn0, nn1);
    const f32x2 ratio2 = pk(ratio0, ratio1);
    const f32x2 one2   = pk(1.0f, 1.0f);

    const float kf  = (float)(l32 + 1);             // this lane's k
    const float mk  = nb * kf;
    const f32x2 mk2 = pk(mk, mk);
    const f32x2 nb2 = pk(nb, nb);

    for (int it = 0; it < n_iters; ++it) {
        // ---- stage both systems' eps (barrier-bracketed fences) ----
        __syncthreads();
        t_sh[2 * hbit + l32]      = eps0;           // 2*hbit == h*64
        t_sh[2 * hbit + 32 + l32] = eps1;
        __syncthreads();

        // ---- batch-issue ALL 16 ds_read_b128 of this half's eps tile.
        // Back-to-back issue pipelines the ~120cy LDS latency once
        // (~180cy total) instead of paying it per-consumer inside C_k.
        const float4* t4 = reinterpret_cast<const float4*>(t_sh);
        float4 va[8], vb[8];
        #pragma unroll
        for (int i = 0; i < 8; ++i) {
            va[i] = t4[(h << 4) + 2 * i];      // eps[8i .. 8i+3]
            vb[i] = t4[(h << 4) + 2 * i + 1];  // eps[8i+4 .. 8i+7]
        }

        // ---- aux inputs (register-only), computed IN the load shadow ----
        const f32x2 x2 = exp_pair(nb2 * pk(eps0, eps1));

        // pin loaded values here: forces the loads (and their single lgkm
        // drain) to complete before C_k compute, and stops the scheduler
        // sinking individual loads back between consumers.
        #pragma unroll
        for (int i = 0; i < 8; ++i) {
            asm volatile("" : "+v"(va[i].x), "+v"(va[i].y), "+v"(va[i].z), "+v"(va[i].w));
            asm volatile("" : "+v"(vb[i].x), "+v"(vb[i].y), "+v"(vb[i].z), "+v"(vb[i].w));
        }

        // ---- C_k: lane k-1 of each half builds all 8 numpy accumulators
        // (identical values/order to R17, pairwise-packed), now from regs.
        // acc2[j] = {acc[2j], acc[2j+1]} of R12.
        f32x2 acc2[4];
        #pragma unroll
        for (int i = 0; i < 8; ++i) {
            const f32x2 r01 = exp_pair(mk2 * pk(va[i].x, va[i].y));
            const f32x2 r23 = exp_pair(mk2 * pk(va[i].z, va[i].w));
            const f32x2 r45 = exp_pair(mk2 * pk(vb[i].x, vb[i].y));
            const f32x2 r67 = exp_pair(mk2 * pk(vb[i].z, vb[i].w));
            if (i == 0) {
                acc2[0] = r01; acc2[1] = r23; acc2[2] = r45; acc2[3] = r67;
            } else {
                acc2[0] += r01; acc2[1] += r23; acc2[2] += r45; acc2[3] += r67;
            }
        }
        // ((a0+a1)+(a2+a3)) + ((a4+a5)+(a6+a7)) -- same tree as R12
        const float Cfull = ((acc2[0].x + acc2[0].y) + (acc2[1].x + acc2[1].y)) +
                            ((acc2[2].x + acc2[2].y) + (acc2[3].x + acc2[3].y));
        // lane hbit + (k-1) holds C[k] of its system

        const float c1A = readlane_f(Cfull, 0);
        const float c1B = readlane_f(Cfull, 32);
        const float c1v = hbit ? c1B : c1A;          // per-half C[1]

        // E[i] = C[i+1]/C[i] (l32==0 junk, never consumed by live lanes)
        const float prevC = __shfl(Cfull, ((l32 - 1) & 31) | hbit);
        const float E     = Cfull * rcp_nr(prevC);

        // ---- preload + pin the 31 E-gathers (R8 win) ----
        float Er[NPART];
        #pragma unroll
        for (int s = 1; s < NPART; ++s) {
            Er[s] = __shfl(E, ((l32 + 1 - s) & 31) | hbit);
            asm volatile("" : "+v"(Er[s]));          // schedule pin only
        }

        // ---- fused sweep + aux (R17 structure; aux pair packed):
        // per-element aux ops/order identical to R12.
        const float invQ0 = rcp_nr(c1v);
        // aux step 0 (prev = 1.0 initially; g*1.0 is exact)
        f32x2 prev2;
        {
            const f32x2 a2 = (x2 * pk(invQ0, invQ0)) * one2;
            prev2 = one2 - a2;
        }
        f32x2 y30_2 = pk(0.0f, 0.0f);
        float invQprev = invQ0;                      // invQ[s-1] carry
        float p = 1.0f;
        #pragma unroll
        for (int s = 1; s < NPART; ++s) {
            const float d = Er[s] * invQprev;
            const float m = d * p;
            p = 1.0f - m;
            const float psA = readlane_f(p, s);
            const float psB = readlane_f(p, 32 + s);
            const float psv = hbit ? psB : psA;
            const float invQs = (float)(s + 1) * rcp_nr(c1v * psv);
            // aux step s (packed; per-half == R12's (x*invQs)*prev; 1-a)
            const f32x2 a2 = (x2 * pk(invQs, invQs)) * prev2;
            prev2 = one2 - a2;
            if (s == NPART - 2) y30_2 = prev2;
            invQprev = invQs;
        }
        const float invQ31 = invQprev;               // invQ[NPART-1]
        const f32x2 Qp1_2  = prev2;
        const f32x2 Qp0_2  = y30_2 * pk(invQ31, invQ31);

        // ---- update + normalize (per-element ops identical to R12) ----
        const f32x2 q2 = (ratio2 * Qp1_2) * pk(rcp_nr(Qp0_2.x), rcp_nr(Qp0_2.y));
        const float en0 = (-ln_acc(q2.x)) * inv_beta;
        const float en1 = (-ln_acc(q2.y)) * inv_beta;

        const f32x2 w2 = nn2 * pk(en0, en1);         // {nn0*en0, nn1*en1}
        const float W = red_np(w2.x, w2.y, l32, hbit);
        const float corr = W * inv_snn;
        eps0 = en0 - corr;
        eps1 = en1 - corr;
    }

    out[sysbase + l32]      = eps0;
    out[sysbase + 32 + l32] = eps1;
}

extern "C" void kernel_launch(void* const* d_in, const int* in_sizes, int n_in,
                              void* d_out, int out_size, void* d_ws, size_t ws_size,
                              hipStream_t stream) {
    const float* n_ptr    = (const float*)d_in[0];
    const float* beta_ptr = (const float*)d_in[1];
    const int*   it_ptr   = (const int*)d_in[2];
    float*       out      = (float*)d_out;

    const int B = in_sizes[0] / PORB;   // 2048 systems
    sinkhorn_kernel<<<B / 2, PORB, 0, stream>>>(n_ptr, beta_ptr, it_ptr, out);
}